// Round 5
// baseline (207.223 us; speedup 1.0000x reference)
//
#include <hip/hip_runtime.h>
#include <hip/hip_bf16.h>

// Shapes: B=16, H=64, W=64, CIN=128, C=256.
// Math identity 1: softmax(.,axis=1).sum(axis=1) == 1  =>  att == v, q/k unused.
// Math identity 2: y = x + x@Wv + bv == x@(Wv+I) + bv  (identity folded into weights).
// Pipeline: x = leaky(BN(conv3x3(in))); y = x@(Wv+I)+bv; out = leaky(LN(y)).
// Intermediate layout: [pixel_pair][co][pl] u32-interleaved for full-sector stores.

typedef __attribute__((ext_vector_type(8))) short short8x;
typedef __attribute__((ext_vector_type(4))) float floatx4;

__device__ __forceinline__ float bf2f(unsigned short u) {
    union { unsigned int i; float f; } v; v.i = ((unsigned int)u) << 16; return v.f;
}
__device__ __forceinline__ unsigned short f2bf(float f) {
    union { float fl; unsigned int i; } v; v.fl = f;
    return (unsigned short)((v.i + 0x7FFFu + ((v.i >> 16) & 1u)) >> 16);
}
__device__ __forceinline__ unsigned int pack2(float a, float b) {
    return (unsigned int)f2bf(a) | ((unsigned int)f2bf(b) << 16);
}
__device__ __forceinline__ float lrelu(float f) { return f > 0.0f ? f : 0.3f * f; }

// ---- prep: transpose+cast weights. cblwt[tap][co][ci]; wvt[co][ci] = Wv^T + I ----
__global__ void prep_w(const float* __restrict__ cbl_w, const float* __restrict__ wv,
                       unsigned short* __restrict__ cblwt, unsigned short* __restrict__ wvt) {
    int t = blockIdx.x * 256 + threadIdx.x;
    if (t < 294912) {
        int ci = t & 127, rest = t >> 7;
        int co = rest & 255, tap = rest >> 8;
        cblwt[t] = f2bf(cbl_w[(tap * 128 + ci) * 256 + co]);
    } else {
        int u = t - 294912;
        int ci = u & 255, co = u >> 8;
        wvt[u] = f2bf(wv[ci * 256 + co] + (ci == co ? 1.0f : 0.0f));
    }
}

// ---- K1: conv3x3 implicit GEMM. Block = 4 rows (256 px) x 256 co, 8 waves.
//      A swizzled in LDS; B triple-buffered via global_load_lds, layout [kc][co]
//      (conflict-free reads), counted vmcnt (never 0 in main loop). ----
__launch_bounds__(512, 2)
__global__ void conv_bn(const float* __restrict__ inp,
                        const unsigned short* __restrict__ wt,
                        const float* __restrict__ cbl_b,
                        unsigned int* __restrict__ xpre32,
                        float* __restrict__ bn_sum, float* __restrict__ bn_sumsq) {
    __shared__ unsigned short a_sh[50688];   // 6*66 px * 128 ci, swizzled, 101376 B
    __shared__ unsigned short b_sh[24576];   // 3 bufs * (4 kc * 256 co * 8ci), 49152 B
    const int h0 = blockIdx.x * 4;
    const int b  = blockIdx.y;
    const int tid = threadIdx.x;
    const int lane = tid & 63, wave = tid >> 6;
    const int l15 = lane & 15, l4 = lane >> 4;
    const int wave_m = wave >> 2, wave_n = wave & 3;

    // ---- stage A: rows h0-1..h0+4, cols -1..64, fp32 -> bf16, swizzled ----
    for (int idx = tid; idx < 6336; idx += 512) {
        const int c  = idx & 15;          // 16B chunk (8 ci)
        const int p  = idx >> 4;
        const int px = p % 66;
        const int r  = p / 66;
        const int gy = h0 + r - 1;
        const int gx = px - 1;
        union { uint4 q; unsigned short s[8]; } pk;
        if ((unsigned)gy < 64u && (unsigned)gx < 64u) {
            const float4* sp = reinterpret_cast<const float4*>(
                inp + (((b * 64 + gy) * 64 + gx) * 128 + c * 8));
            const float4 f0 = sp[0], f1 = sp[1];
            pk.s[0]=f2bf(f0.x); pk.s[1]=f2bf(f0.y); pk.s[2]=f2bf(f0.z); pk.s[3]=f2bf(f0.w);
            pk.s[4]=f2bf(f1.x); pk.s[5]=f2bf(f1.y); pk.s[6]=f2bf(f1.z); pk.s[7]=f2bf(f1.w);
        } else {
            pk.q = make_uint4(0u, 0u, 0u, 0u);
        }
        const int byte = ((r * 66 + px) * 256 + c * 16) ^ ((px & 7) << 4);
        *reinterpret_cast<uint4*>(reinterpret_cast<char*>(a_sh) + byte) = pk.q;
    }
    __syncthreads();

    floatx4 acc[8][4];
    #pragma unroll
    for (int m = 0; m < 8; ++m)
        #pragma unroll
        for (int n = 0; n < 4; ++n)
            acc[m][n] = (floatx4){0.f, 0.f, 0.f, 0.f};

    // B stage (16 KB): layout byte = kc*4096 + co*16, kc = ci-chunk (8 ci each).
    // LDS line li = wave*2+j -> kc = li>>2, co_block = li&3, lane -> co.
    auto b_issue = [&](int tap, int kk, int buf) {
        #pragma unroll
        for (int j = 0; j < 2; ++j) {
            const int li = wave * 2 + j;
            const int kc = li >> 2;
            const int co = (li & 3) * 64 + lane;
            const unsigned short* src = wt + ((tap * 256 + co) * 128 + kk * 32 + kc * 8);
            unsigned short* dst = &b_sh[buf * 8192 + li * 512];  // wave-uniform base
            __builtin_amdgcn_global_load_lds(
                (const __attribute__((address_space(1))) void*)src,
                (__attribute__((address_space(3))) void*)dst, 16, 0, 0);
        }
    };
    auto c_step = [&](int dy, int dx, int kk, int buf) {
        short8x av[8], bbv[4];
        const char* bb = reinterpret_cast<const char*>(b_sh) + buf * 16384;
        #pragma unroll
        for (int n = 0; n < 4; ++n)
            bbv[n] = *reinterpret_cast<const short8x*>(
                bb + l4 * 4096 + (wave_n * 64 + n * 16 + l15) * 16);
        const char* ab = reinterpret_cast<const char*>(a_sh);
        #pragma unroll
        for (int m = 0; m < 8; ++m) {
            const int col = (m & 3) * 16 + l15 + dx;
            const int row = wave_m * 2 + (m >> 2) + dy;
            const int byte = ((row * 66 + col) * 256 + kk * 64 + l4 * 16) ^ ((col & 7) << 4);
            av[m] = *reinterpret_cast<const short8x*>(ab + byte);
        }
        __builtin_amdgcn_s_setprio(1);
        #pragma unroll
        for (int m = 0; m < 8; ++m)
            #pragma unroll
            for (int n = 0; n < 4; ++n)
                acc[m][n] = __builtin_amdgcn_mfma_f32_16x16x32_bf16(
                    av[m], bbv[n], acc[m][n], 0, 0, 0);
        __builtin_amdgcn_s_setprio(0);
    };

    // prologue: stages 0,1 in flight
    b_issue(0, 0, 0);
    b_issue(0, 1, 1);

    // main loop: stage s = tap*4+kk. wait own stage-s loads, barrier (now all
    // waves' stage-s data in LDS), issue s+2 (its buffer was consumed in s-1),
    // then compute.
    int buf = 0;
    for (int tap = 0; tap < 8; ++tap) {
        const int dy = tap / 3, dx = tap % 3;
        #pragma unroll
        for (int kk = 0; kk < 4; ++kk) {
            asm volatile("s_waitcnt vmcnt(2)" ::: "memory");
            __builtin_amdgcn_s_barrier();
            {
                const int ntap = tap + (kk >> 1);
                const int nkk  = (kk + 2) & 3;
                const int nbuf = (buf == 0) ? 2 : buf - 1;  // (s+2)%3
                b_issue(ntap, nkk, nbuf);
            }
            __builtin_amdgcn_sched_barrier(0);
            c_step(dy, dx, kk, buf);
            buf = (buf == 2) ? 0 : buf + 1;
        }
    }
    // tail: tap 8 (dy=2,dx=2), s=32..35; buf enters as 2
    asm volatile("s_waitcnt vmcnt(2)" ::: "memory");
    __builtin_amdgcn_s_barrier();
    b_issue(8, 2, 1);
    __builtin_amdgcn_sched_barrier(0);
    c_step(2, 2, 0, 2);
    asm volatile("s_waitcnt vmcnt(2)" ::: "memory");
    __builtin_amdgcn_s_barrier();
    b_issue(8, 3, 2);
    __builtin_amdgcn_sched_barrier(0);
    c_step(2, 2, 1, 0);
    asm volatile("s_waitcnt vmcnt(2)" ::: "memory");
    __builtin_amdgcn_s_barrier();
    __builtin_amdgcn_sched_barrier(0);
    c_step(2, 2, 2, 1);
    asm volatile("s_waitcnt vmcnt(0)" ::: "memory");
    __builtin_amdgcn_s_barrier();
    __builtin_amdgcn_sched_barrier(0);
    c_step(2, 2, 3, 2);

    // epilogue: +bias, paired u32 stores (full 64B sectors), BN partial sums
    const int ppbase = (b * 4096 + h0 * 64) >> 1;
    #pragma unroll
    for (int n = 0; n < 4; ++n) {
        const int co = wave_n * 64 + n * 16 + l15;
        const float bias = cbl_b[co];
        float s = 0.f, s2 = 0.f;
        #pragma unroll
        for (int m = 0; m < 8; ++m) {
            const int pp0 = ppbase + ((wave_m * 128 + m * 16 + l4 * 4) >> 1);
            float v0 = acc[m][n][0] + bias, v1 = acc[m][n][1] + bias;
            float v2 = acc[m][n][2] + bias, v3 = acc[m][n][3] + bias;
            xpre32[pp0 * 256 + co]       = pack2(v0, v1);
            xpre32[(pp0 + 1) * 256 + co] = pack2(v2, v3);
            s += v0 + v1 + v2 + v3;
            s2 += v0 * v0 + v1 * v1 + v2 * v2 + v3 * v3;
        }
        s  += __shfl_xor(s, 16);  s  += __shfl_xor(s, 32);
        s2 += __shfl_xor(s2, 16); s2 += __shfl_xor(s2, 32);
        if (l4 == 0) {
            atomicAdd(&bn_sum[co], s);
            atomicAdd(&bn_sumsq[co], s2);
        }
    }
}

// ---- K2: BN-apply + leaky -> 256px x-tile in LDS (de-interleave + swizzle);
//      y = x@(Wv+I)+bv via MFMA (B reg-prefetch from L2); paired u32 stores;
//      per-sample LN partial sums. ----
__launch_bounds__(512, 2)
__global__ void fused_mid(const unsigned int* __restrict__ xpre32,
                          const unsigned short* __restrict__ wvt,
                          const float* __restrict__ bv,
                          const float* __restrict__ bn_sum, const float* __restrict__ bn_sumsq,
                          const float* __restrict__ bn_gamma, const float* __restrict__ bn_beta,
                          unsigned int* __restrict__ yws32,
                          float* __restrict__ ln_sum, float* __restrict__ ln_sumsq) {
    __shared__ unsigned short x_sh[65536];   // 256 px x 256 ci, swizzled, 131072 B
    __shared__ float s_scale[256], s_shift[256];
    __shared__ float s_red[16];
    const int tid = threadIdx.x;
    const int pbase  = blockIdx.y * 4096 + blockIdx.x * 256;  // 256 contiguous pixels
    const int ppbase = pbase >> 1;

    if (tid < 256) {
        const float mean = bn_sum[tid] * (1.0f / 65536.0f);
        const float var  = bn_sumsq[tid] * (1.0f / 65536.0f) - mean * mean;
        const float sc = bn_gamma[tid] * rsqrtf(var + 1e-3f);
        s_scale[tid] = sc;
        s_shift[tid] = bn_beta[tid] - mean * sc;
    }
    __syncthreads();

    const int c0 = (tid & 63) * 4;
    float scv[4], shv[4];
    #pragma unroll
    for (int c = 0; c < 4; ++c) { scv[c] = s_scale[c0 + c]; shv[c] = s_shift[c0 + c]; }

    char* xb = reinterpret_cast<char*>(x_sh);
    #pragma unroll 4
    for (int i = 0; i < 16; ++i) {
        const int idx = tid + i * 512;
        const int pp  = idx >> 6;         // 0..127 (idx&63 == tid&63, scv valid)
        const int px0 = pp * 2;
        union { uint4 q; unsigned int u[4]; } iv;
        iv.q = *reinterpret_cast<const uint4*>(xpre32 + (ppbase + pp) * 256 + c0);
        union { unsigned long long d; unsigned short s[4]; } w0, w1;
        #pragma unroll
        for (int c = 0; c < 4; ++c) {
            const unsigned int v = iv.u[c];
            w0.s[c] = f2bf(lrelu(fmaf(bf2f((unsigned short)(v & 0xffff)), scv[c], shv[c])));
            w1.s[c] = f2bf(lrelu(fmaf(bf2f((unsigned short)(v >> 16)),    scv[c], shv[c])));
        }
        const int b0 = (px0 * 512 + c0 * 2) ^ ((px0 & 7) << 4);
        const int b1 = ((px0 + 1) * 512 + c0 * 2) ^ (((px0 + 1) & 7) << 4);
        *reinterpret_cast<unsigned long long*>(xb + b0) = w0.d;
        *reinterpret_cast<unsigned long long*>(xb + b1) = w1.d;
    }
    __syncthreads();

    const int lane = tid & 63, wave = tid >> 6;
    const int l15 = lane & 15, l4 = lane >> 4;
    const int wave_m = wave >> 2, wave_n = wave & 3;

    floatx4 acc[8][4];
    #pragma unroll
    for (int m = 0; m < 8; ++m)
        #pragma unroll
        for (int n = 0; n < 4; ++n)
            acc[m][n] = (floatx4){0.f, 0.f, 0.f, 0.f};

    short8x bcur[4], bnxt[4];
    #pragma unroll
    for (int n = 0; n < 4; ++n)
        bcur[n] = *reinterpret_cast<const short8x*>(
            wvt + (wave_n * 64 + n * 16 + l15) * 256 + l4 * 8);

    #pragma unroll
    for (int kk = 0; kk < 8; ++kk) {
        if (kk < 7) {
            #pragma unroll
            for (int n = 0; n < 4; ++n)
                bnxt[n] = *reinterpret_cast<const short8x*>(
                    wvt + (wave_n * 64 + n * 16 + l15) * 256 + (kk + 1) * 32 + l4 * 8);
        }
        short8x av[8];
        #pragma unroll
        for (int m = 0; m < 8; ++m) {
            const int p = wave_m * 128 + m * 16 + l15;
            const int byte = (p * 512 + kk * 64 + l4 * 16) ^ ((p & 7) << 4);
            av[m] = *reinterpret_cast<const short8x*>(xb + byte);
        }
        __builtin_amdgcn_s_setprio(1);
        #pragma unroll
        for (int m = 0; m < 8; ++m)
            #pragma unroll
            for (int n = 0; n < 4; ++n)
                acc[m][n] = __builtin_amdgcn_mfma_f32_16x16x32_bf16(
                    av[m], bcur[n], acc[m][n], 0, 0, 0);
        __builtin_amdgcn_s_setprio(0);
        if (kk < 7) {
            #pragma unroll
            for (int n = 0; n < 4; ++n) bcur[n] = bnxt[n];
        }
    }

    float ls = 0.f, ls2 = 0.f;
    #pragma unroll
    for (int n = 0; n < 4; ++n) {
        const int co = wave_n * 64 + n * 16 + l15;
        const float bias = bv[co];
        #pragma unroll
        for (int m = 0; m < 8; ++m) {
            const int pp0 = ppbase + ((wave_m * 128 + m * 16 + l4 * 4) >> 1);
            const float y0 = acc[m][n][0] + bias, y1 = acc[m][n][1] + bias;
            const float y2 = acc[m][n][2] + bias, y3 = acc[m][n][3] + bias;
            yws32[pp0 * 256 + co]       = pack2(y0, y1);
            yws32[(pp0 + 1) * 256 + co] = pack2(y2, y3);
            ls += y0 + y1 + y2 + y3;
            ls2 += y0 * y0 + y1 * y1 + y2 * y2 + y3 * y3;
        }
    }
    #pragma unroll
    for (int off = 32; off > 0; off >>= 1) {
        ls += __shfl_xor(ls, off);
        ls2 += __shfl_xor(ls2, off);
    }
    if (lane == 0) { s_red[wave] = ls; s_red[wave + 8] = ls2; }
    __syncthreads();
    if (tid == 0) {
        float a = 0.f, c = 0.f;
        #pragma unroll
        for (int w = 0; w < 8; ++w) { a += s_red[w]; c += s_red[w + 8]; }
        atomicAdd(&ln_sum[blockIdx.y], a);
        atomicAdd(&ln_sumsq[blockIdx.y], c);
    }
}

// ---- K3: LayerNorm + per-element affine + leaky -> f32 out.
//      yws is [pp][co][pl] u32-interleaved; all accesses stay coalesced. ----
__global__ void final_ln(const unsigned int* __restrict__ yws32,
                         const float* __restrict__ ln_sum, const float* __restrict__ ln_sumsq,
                         const float* __restrict__ ln_gamma, const float* __restrict__ ln_beta,
                         float* __restrict__ out) {
    const int i = blockIdx.x * 256 + threadIdx.x;   // 8M u32s
    const int pp = i >> 8, co = i & 255;
    const int b  = pp >> 11;                         // 2048 pixel-pairs per sample
    const float mean = ln_sum[b] * (1.0f / 1048576.0f);
    const float var  = ln_sumsq[b] * (1.0f / 1048576.0f) - mean * mean;
    const float inv  = rsqrtf(var + 1e-3f);
    const unsigned int v = yws32[i];
    const int g0 = ((pp & 2047) * 2) * 256 + co;     // (h,w,c) affine index, px even
    const float gm0 = ln_gamma[g0],       bt0 = ln_beta[g0];
    const float gm1 = ln_gamma[g0 + 256], bt1 = ln_beta[g0 + 256];
    out[pp * 512 + co]       = lrelu((bf2f((unsigned short)(v & 0xffff)) - mean) * inv * gm0 + bt0);
    out[pp * 512 + 256 + co] = lrelu((bf2f((unsigned short)(v >> 16))    - mean) * inv * gm1 + bt1);
}

extern "C" void kernel_launch(void* const* d_in, const int* in_sizes, int n_in,
                              void* d_out, int out_size, void* d_ws, size_t ws_size,
                              hipStream_t stream) {
    (void)in_sizes; (void)n_in; (void)out_size; (void)ws_size;
    const float* inputs   = (const float*)d_in[0];
    const float* cbl_w    = (const float*)d_in[1];
    const float* cbl_b    = (const float*)d_in[2];
    const float* bn_gamma = (const float*)d_in[3];
    const float* bn_beta  = (const float*)d_in[4];
    // d_in[5..8] (wq,bq,wk,bk) are mathematically dead: softmax-col-sums == 1
    const float* wv       = (const float*)d_in[9];
    const float* bv       = (const float*)d_in[10];
    const float* ln_gamma = (const float*)d_in[11];
    const float* ln_beta  = (const float*)d_in[12];
    float* out = (float*)d_out;

    char* ws = (char*)d_ws;
    unsigned int* xpre32  = (unsigned int*)(ws + 0);            // 32 MiB
    unsigned int* yws32   = (unsigned int*)(ws + 33554432);     // 32 MiB
    unsigned short* cblwt = (unsigned short*)(ws + 67108864);   // 576 KiB
    unsigned short* wvt   = (unsigned short*)(ws + 67698688);   // 128 KiB
    float* accum          = (float*)(ws + 67829760);            // 544 floats
    float* bn_sum   = accum;
    float* bn_sumsq = accum + 256;
    float* ln_sum   = accum + 512;
    float* ln_sumsq = accum + 528;

    hipMemsetAsync(accum, 0, 544 * sizeof(float), stream);
    prep_w<<<1408, 256, 0, stream>>>(cbl_w, wv, cblwt, wvt);
    conv_bn<<<dim3(16, 16), 512, 0, stream>>>(inputs, cblwt, cbl_b, xpre32, bn_sum, bn_sumsq);
    fused_mid<<<dim3(16, 16), 512, 0, stream>>>(xpre32, wvt, bv, bn_sum, bn_sumsq,
                                                bn_gamma, bn_beta, yws32, ln_sum, ln_sumsq);
    final_ln<<<32768, 256, 0, stream>>>(yws32, ln_sum, ln_sumsq, ln_gamma, ln_beta, out);
}